// Round 7
// baseline (233.882 us; speedup 1.0000x reference)
//
#include <hip/hip_runtime.h>
#include <hip/hip_bf16.h>
#include <stdint.h>

#define B_    4
#define N_    8192
#define K_    32
#define CX    67      // 3 + C_IN
#define CMID  64
#define COUT  128

#define TPW   8                   // points per wave
#define NWG   2048                // 2048 WG * 2 waves * 8 pts = 32768 points
#define XBUF  9216                // per-point stage: 72 rows x 128B (f32 [c][k])
#define XPW   (2 * XBUF)          // per-wave double buffer
#define XTOT  (2 * XPW)           // 2 waves = 36864 B
#define TRS   12288               // transient weight-staging region
#define W1TS  96                  // W1 transient row stride (elems)
#define W2TS  72                  // W2 transient row stride (elems)

typedef __bf16 bf16_t;
typedef bf16_t bf16x8 __attribute__((ext_vector_type(8)));
typedef float  f32x4  __attribute__((ext_vector_type(4)));

#define WAITV(n_) do { \
    asm volatile("s_waitcnt vmcnt(" #n_ ")" ::: "memory"); \
    __builtin_amdgcn_sched_barrier(0); } while (0)

__device__ __forceinline__ uint32_t pack2bf(float a, float b) {
    union { bf16_t h[2]; uint32_t u; } x;
    x.h[0] = (bf16_t)a; x.h[1] = (bf16_t)b;
    return x.u;
}

template<bool DIRECT>
__global__ __launch_bounds__(128, 2)
void sa_main(const float* __restrict__ dp, const float* __restrict__ fj,
             const float* __restrict__ W1, const float* __restrict__ b1,
             const float* __restrict__ W2, const float* __restrict__ b2,
             float* __restrict__ dst)
{
    __shared__ __align__(16) char smem[XTOT + TRS];   // 49152 B -> 3 WG/CU

    const int tid  = threadIdx.x;
    const int wave = tid >> 6;
    const int lane = tid & 63;
    const int lrow = lane & 15;   // MFMA row/col within 16-tile; kpos pair {2*lrow, 2*lrow+1}
    const int g    = lane >> 4;   // 16-lane group (fragment k-group)

    const size_t plane = (size_t)N_ * K_;
    const int wg = blockIdx.x;
    const int b  = wg >> 9;                               // 512 WGs per batch
    const int n0 = ((wg & 511) << 4) + wave * TPW;        // this wave's first point

    const float* dpb = dp + (size_t)b * 3  * plane;
    const float* fjb = fj + (size_t)b * 64 * plane;

    // ---- per-lane global addresses for the 9 stage instructions (point n0) ----
    const char* ga[9];
    {
        const int q = lane & 7;
        #pragma unroll
        for (int j = 0; j < 9; ++j) {
            int c = j * 8 + (lane >> 3);
            if (c > 66) c = 66;                           // clamp: finite real data
            const float* p = (c < 3) ? (dpb + (size_t)c * plane)
                                     : (fjb + (size_t)(c - 3) * plane);
            ga[j] = (const char*)(p + (size_t)n0 * K_ + q * 4);
        }
    }

    char* xbase = smem + wave * XPW;

    auto stage = [&](int buf) {   // 9 async DMA instrs, 1 KB each -> [c][k] f32, 72 rows
        char* ld = xbase + buf * XBUF;
        #pragma unroll
        for (int j = 0; j < 9; ++j)
            __builtin_amdgcn_global_load_lds(
                (const __attribute__((address_space(1))) void*)ga[j],
                (__attribute__((address_space(3))) void*)(ld + j * 1024),
                16, 0, 0);
    };
    auto advance = [&]() {
        #pragma unroll
        for (int j = 0; j < 9; ++j) ga[j] += 128;         // next point (same chans)
    };

    // prefetch points t=0, t=1 (land while the weight prologue runs)
    stage(0); advance();
    stage(1); advance();                                  // ga now targets t=2

    // ---- weight prologue via transient LDS (syncthreads drains prefetch too) ----
    bf16_t* trs = (bf16_t*)(smem + XTOT);
    // W1, rows PERMUTED: slot s=(rt*16+4q+i) holds out-chan 32*(rt>>1)+8q+4*(rt&1)+i
    for (int i = tid; i < 64 * W1TS; i += 128) {
        int s = i / W1TS, c = i - s * W1TS;
        int rt = s >> 4, r = s & 15, qq = r >> 2, ii = r & 3;
        int o = 32 * (rt >> 1) + 8 * qq + 4 * (rt & 1) + ii;
        trs[i] = (c < CX) ? (bf16_t)W1[o * CX + c] : (bf16_t)0.f;
    }
    __syncthreads();
    bf16x8 w1f[3][4];
    #pragma unroll
    for (int kc = 0; kc < 3; ++kc)
        #pragma unroll
        for (int rt = 0; rt < 4; ++rt)
            w1f[kc][rt] = *(const bf16x8*)&trs[(rt * 16 + lrow) * W1TS + kc * 32 + g * 8];
    __syncthreads();
    // W2 in two half-stages (64 rows each)
    bf16x8 w2f[2][8];
    #pragma unroll 1
    for (int h = 0; h < 2; ++h) {
        for (int i = tid; i < 64 * W2TS; i += 128) {
            int o = i / W2TS, c = i - o * W2TS;
            trs[i] = (c < CMID) ? (bf16_t)W2[(h * 64 + o) * CMID + c] : (bf16_t)0.f;
        }
        __syncthreads();
        #pragma unroll
        for (int ot = 0; ot < 4; ++ot) {
            w2f[0][h * 4 + ot] = *(const bf16x8*)&trs[(ot * 16 + lrow) * W2TS +  0 + g * 8];
            w2f[1][h * 4 + ot] = *(const bf16x8*)&trs[(ot * 16 + lrow) * W2TS + 32 + g * 8];
        }
        __syncthreads();
    }

    f32x4 b1f[4];   // permuted to match W1 row order
    #pragma unroll
    for (int rt = 0; rt < 4; ++rt)
        b1f[rt] = *(const f32x4*)(b1 + 32 * (rt >> 1) + 8 * g + 4 * (rt & 1));
    float b2f[8];
    #pragma unroll
    for (int ot = 0; ot < 8; ++ot) b2f[ot] = b2[ot * 16 + lrow];

    // ---- one point: read frags from LDS -> reissue DMA -> MFMA -> pool -> store ----
    auto body = [&](int t, int cur, bool reissue) {
        const int n = n0 + t;
        const float2* xb = (const float2*)(xbase + cur * XBUF);   // [c][kpair] rows of 16 float2

        bf16x8 f0[3], f1[3];
        #pragma unroll
        for (int kc = 0; kc < 2; ++kc) {
            const int cb = kc * 32 + g * 8;
            float2 e0 = xb[(cb + 0) * 16 + lrow], e1 = xb[(cb + 1) * 16 + lrow];
            float2 e2 = xb[(cb + 2) * 16 + lrow], e3 = xb[(cb + 3) * 16 + lrow];
            float2 e4 = xb[(cb + 4) * 16 + lrow], e5 = xb[(cb + 5) * 16 + lrow];
            float2 e6 = xb[(cb + 6) * 16 + lrow], e7 = xb[(cb + 7) * 16 + lrow];
            union { uint32_t u[4]; bf16x8 w; } c0, c1;
            c0.u[0] = pack2bf(e0.x, e1.x); c0.u[1] = pack2bf(e2.x, e3.x);
            c0.u[2] = pack2bf(e4.x, e5.x); c0.u[3] = pack2bf(e6.x, e7.x);
            c1.u[0] = pack2bf(e0.y, e1.y); c1.u[1] = pack2bf(e2.y, e3.y);
            c1.u[2] = pack2bf(e4.y, e5.y); c1.u[3] = pack2bf(e6.y, e7.y);
            f0[kc] = c0.w; f1[kc] = c1.w;
        }
        {   // kc=2: chans 64..66 real; g>0 / e>2 slots hit finite garbage x zero-W1
            int r0 = 64 + g * 8;
            int c0r = (r0     > 71) ? 71 : r0;
            int c1r = (r0 + 1 > 71) ? 71 : r0 + 1;
            int c2r = (r0 + 2 > 71) ? 71 : r0 + 2;
            float2 e0 = xb[c0r * 16 + lrow], e1 = xb[c1r * 16 + lrow], e2 = xb[c2r * 16 + lrow];
            union { uint32_t u[4]; bf16x8 w; } c0, c1;
            c0.u[0] = pack2bf(e0.x, e1.x); c0.u[1] = pack2bf(e2.x, 0.f);
            c0.u[2] = 0; c0.u[3] = 0;
            c1.u[0] = pack2bf(e0.y, e1.y); c1.u[1] = pack2bf(e2.y, 0.f);
            c1.u[2] = 0; c1.u[3] = 0;
            f0[2] = c0.w; f1[2] = c1.w;
        }

        // all X ds_reads retired -> safe to refill this buffer for point t+2
        asm volatile("s_waitcnt lgkmcnt(0)" ::: "memory");
        __builtin_amdgcn_sched_barrier(0);
        if (reissue) stage(cur);

        // ---- layer 1: acc = W1(regs,A) * X(regs,B), both kpos halves ----
        f32x4 acc0[4] = {}, acc1v[4] = {};
        __builtin_amdgcn_s_setprio(1);
        #pragma unroll
        for (int kc = 0; kc < 3; ++kc) {
            #pragma unroll
            for (int rt = 0; rt < 4; ++rt) {
                acc0[rt]  = __builtin_amdgcn_mfma_f32_16x16x32_bf16(w1f[kc][rt], f0[kc], acc0[rt], 0, 0, 0);
                acc1v[rt] = __builtin_amdgcn_mfma_f32_16x16x32_bf16(w1f[kc][rt], f1[kc], acc1v[rt], 0, 0, 0);
            }
        }
        __builtin_amdgcn_s_setprio(0);

        // ---- epilogue 1: bias+relu -> pack -> layer-2 A-frags directly (no LDS) ----
        bf16x8 a2f0[2], a2f1[2];
        #pragma unroll
        for (int kc2 = 0; kc2 < 2; ++kc2) {
            union { uint32_t u[4]; bf16x8 w; } c0, c1;
            #pragma unroll
            for (int hh = 0; hh < 2; ++hh) {
                const int rt = 2 * kc2 + hh;
                float h0 = fmaxf(acc0[rt][0] + b1f[rt][0], 0.f);
                float h1 = fmaxf(acc0[rt][1] + b1f[rt][1], 0.f);
                float h2 = fmaxf(acc0[rt][2] + b1f[rt][2], 0.f);
                float h3 = fmaxf(acc0[rt][3] + b1f[rt][3], 0.f);
                c0.u[hh * 2 + 0] = pack2bf(h0, h1);
                c0.u[hh * 2 + 1] = pack2bf(h2, h3);
                float j0 = fmaxf(acc1v[rt][0] + b1f[rt][0], 0.f);
                float j1 = fmaxf(acc1v[rt][1] + b1f[rt][1], 0.f);
                float j2 = fmaxf(acc1v[rt][2] + b1f[rt][2], 0.f);
                float j3 = fmaxf(acc1v[rt][3] + b1f[rt][3], 0.f);
                c1.u[hh * 2 + 0] = pack2bf(j0, j1);
                c1.u[hh * 2 + 1] = pack2bf(j2, j3);
            }
            a2f0[kc2] = c0.w; a2f1[kc2] = c1.w;
        }

        // ---- layer 2: A = packed H (regs), B = W2 (regs); D rows = k-positions ----
        float macc[8];
        __builtin_amdgcn_s_setprio(1);
        #pragma unroll
        for (int ot = 0; ot < 8; ++ot) {
            f32x4 t0 = {}, t1 = {};
            t0 = __builtin_amdgcn_mfma_f32_16x16x32_bf16(a2f0[0], w2f[0][ot], t0, 0, 0, 0);
            t0 = __builtin_amdgcn_mfma_f32_16x16x32_bf16(a2f0[1], w2f[1][ot], t0, 0, 0, 0);
            t1 = __builtin_amdgcn_mfma_f32_16x16x32_bf16(a2f1[0], w2f[0][ot], t1, 0, 0, 0);
            t1 = __builtin_amdgcn_mfma_f32_16x16x32_bf16(a2f1[1], w2f[1][ot], t1, 0, 0, 0);
            float m0 = fmaxf(fmaxf(t0[0], t0[1]), fmaxf(t0[2], t0[3]));
            float m1 = fmaxf(fmaxf(t1[0], t1[1]), fmaxf(t1[2], t1[3]));
            macc[ot] = fmaxf(m0, m1);
        }
        __builtin_amdgcn_s_setprio(0);

        // ---- cross-group pool (xor16 + xor32), bias, relu ----
        #pragma unroll
        for (int ot = 0; ot < 8; ++ot) {
            float vv = macc[ot];
            vv = fmaxf(vv, __shfl_xor(vv, 16, 64));
            vv = fmaxf(vv, __shfl_xor(vv, 32, 64));
            macc[ot] = fmaxf(vv + b2f[ot], 0.f);
        }
        float oa = (g == 0) ? macc[0] : (g == 1) ? macc[2] : (g == 2) ? macc[4] : macc[6];
        float ob = (g == 0) ? macc[1] : (g == 1) ? macc[3] : (g == 2) ? macc[5] : macc[7];
        const int ca = g * 32 + lrow;
        const int cb2 = g * 32 + 16 + lrow;
        if (DIRECT) {
            float* op = dst + (size_t)b * COUT * N_ + n;
            op[(size_t)ca * N_]  = oa;
            op[(size_t)cb2 * N_] = ob;
        } else {
            float* wp = dst + ((size_t)(b * N_ + n)) * COUT;   // ws[b][n][c]
            wp[ca]  = oa;
            wp[cb2] = ob;
        }
    };

    // ---- counted-vmcnt pipeline (ledger: see theory; 2 stores/body included) ----
    WAITV(9);  body(0, 0, true);  advance();
    WAITV(11); body(1, 1, true);  advance();
    #pragma unroll 1
    for (int t = 2; t <= TPW - 3; ++t) {
        WAITV(13);
        body(t, t & 1, true);
        if (t <= TPW - 4) advance();
    }
    WAITV(13); body(TPW - 2, (TPW - 2) & 1, false);
    WAITV(4);  body(TPW - 1, (TPW - 1) & 1, false);
}

// ws[b][n][c] -> out[b][c][n], full lines on both sides
__global__ __launch_bounds__(256)
void sa_transpose(const float* __restrict__ ws, float* __restrict__ out)
{
    __shared__ float tile[32][136];
    const int t  = threadIdx.x;
    const int i  = blockIdx.x;         // 0..1023
    const int b  = i >> 8;
    const int n0 = (i & 255) << 5;

    const float* rp = ws + ((size_t)(b * N_ + n0)) * COUT;
    #pragma unroll
    for (int r = 0; r < 4; ++r) {
        int flat = (r * 256 + t) * 4;
        int nl = flat >> 7, c = flat & 127;
        float4 v = *(const float4*)(rp + (size_t)nl * COUT + c);
        *(float4*)&tile[nl][c] = v;
    }
    __syncthreads();
    float* op = out + (size_t)b * COUT * N_ + n0;
    const int nl4 = (t & 7) << 2;
    #pragma unroll
    for (int r2 = 0; r2 < 4; ++r2) {
        int c = r2 * 32 + (t >> 3);
        float4 o4;
        o4.x = tile[nl4 + 0][c];
        o4.y = tile[nl4 + 1][c];
        o4.z = tile[nl4 + 2][c];
        o4.w = tile[nl4 + 3][c];
        *(float4*)(op + (size_t)c * N_ + nl4) = o4;
    }
}

extern "C" void kernel_launch(void* const* d_in, const int* in_sizes, int n_in,
                              void* d_out, int out_size, void* d_ws, size_t ws_size,
                              hipStream_t stream) {
    // inputs: 0=p (unused), 1=f (unused), 2=dp, 3=fj, 4=W1, 5=b1, 6=W2, 7=b2
    const float* dp = (const float*)d_in[2];
    const float* fj = (const float*)d_in[3];
    const float* W1 = (const float*)d_in[4];
    const float* b1 = (const float*)d_in[5];
    const float* W2 = (const float*)d_in[6];
    const float* b2 = (const float*)d_in[7];
    float* out = (float*)d_out;

    const size_t ws_need = (size_t)B_ * N_ * COUT * sizeof(float);
    if (ws_size >= ws_need) {
        float* ws = (float*)d_ws;
        hipLaunchKernelGGL((sa_main<false>), dim3(NWG), dim3(128), 0, stream,
                           dp, fj, W1, b1, W2, b2, ws);
        hipLaunchKernelGGL(sa_transpose, dim3(1024), dim3(256), 0, stream, ws, out);
    } else {
        hipLaunchKernelGGL((sa_main<true>), dim3(NWG), dim3(128), 0, stream,
                           dp, fj, W1, b1, W2, b2, out);
    }
}

// Round 9
// 154.993 us; speedup vs baseline: 1.5090x; 1.5090x over previous
//
#include <hip/hip_runtime.h>
#include <hip/hip_bf16.h>
#include <stdint.h>

#define B_    4
#define N_    8192
#define K_    32
#define CX    67      // 3 + C_IN
#define CMID  64
#define COUT  128

#define NT    8          // points per tile
#define TPW   4          // tiles per WG (32 points per WG)
#define PBS   1076       // dwords per point-block (67 rows x 16 pair-dwords + 4 pad)
#define XBUFD (NT * PBS) // 8608 dwords per buffer (34,432 B)
#define NWGM  1024       // 1024 WG x 32 points = 32768

typedef __bf16 bf16_t;
typedef bf16_t bf16x8 __attribute__((ext_vector_type(8)));
typedef float  f32x4  __attribute__((ext_vector_type(4)));

__device__ __forceinline__ uint32_t pack2bf(float a, float b) {
    union { bf16_t h[2]; uint32_t u; } x;
    x.h[0] = (bf16_t)a; x.h[1] = (bf16_t)b;
    return x.u;
}

template<bool DIRECT>
__global__ __launch_bounds__(256, 2)
void sa_main(const float* __restrict__ dp, const float* __restrict__ fj,
             const float* __restrict__ W1, const float* __restrict__ b1,
             const float* __restrict__ W2, const float* __restrict__ b2,
             float* __restrict__ dst)
{
    __shared__ uint32_t lds_[2 * XBUFD];   // 68,864 B -> 2 WG/CU

    const int tid  = threadIdx.x;
    const int wave = tid >> 6;
    const int lane = tid & 63;
    const int lrow = lane & 15;   // MFMA row/col; kpos pair {2*lrow, 2*lrow+1}
    const int g    = lane >> 4;   // 16-lane group (fragment k-group)

    const size_t plane = (size_t)N_ * K_;
    const int wg = blockIdx.x;
    const int b  = wg >> 8;                 // 256 WGs per batch
    const int n0 = (wg & 255) << 5;         // 32 consecutive points per WG

    const float* dpb = dp + (size_t)b * 3  * plane;
    const float* fjb = fj + (size_t)b * 64 * plane;
    const float* dp_l = dpb + (size_t)n0 * K_ + (lane << 2);   // lane*16B within row
    const float* fj_l = fjb + (size_t)n0 * K_ + (lane << 2);

    const int pt_l = lane >> 3, q_l = lane & 7;   // staging: lane -> (point, k-quad)

    // rows r = wave + 4*i ; clusters A: i 0..5, B: 6..11, C: 12..NR-1
    const int NR = (wave < 3) ? 17 : 16;
    const int NC = NR - 12;                 // 5 or 4

    float4 vA[6], vB[6], vC[5];

    auto rowp = [&](int i) -> const float* {
        const int r = wave + 4 * i;
        return (r < 3) ? (dp_l + (size_t)r * plane)
                       : (fj_l + (size_t)(r - 3) * plane);
    };
    auto issueA = [&](int t) {
        #pragma unroll
        for (int i = 0; i < 6; ++i) vA[i] = *(const float4*)(rowp(i) + t * (NT * K_));
    };
    auto issueB = [&](int t) {
        #pragma unroll
        for (int i = 0; i < 6; ++i) vB[i] = *(const float4*)(rowp(6 + i) + t * (NT * K_));
    };
    auto issueC = [&](int t) {
        #pragma unroll
        for (int i = 0; i < 5; ++i)
            if (i < NC) vC[i] = *(const float4*)(rowp(12 + i) + t * (NT * K_));
    };
    auto wr1 = [&](uint32_t* X, int i, const float4& v) {
        const int r = wave + 4 * i;
        *(uint2*)&X[r * 16] = make_uint2(pack2bf(v.x, v.y), pack2bf(v.z, v.w));
    };
    auto writeA = [&](int nxt) {
        uint32_t* X = lds_ + nxt * XBUFD + pt_l * PBS + (q_l << 1);
        #pragma unroll
        for (int i = 0; i < 6; ++i) wr1(X, i, vA[i]);
    };
    auto writeB = [&](int nxt) {
        uint32_t* X = lds_ + nxt * XBUFD + pt_l * PBS + (q_l << 1);
        #pragma unroll
        for (int i = 0; i < 6; ++i) wr1(X, 6 + i, vB[i]);
    };
    auto writeC = [&](int nxt) {
        uint32_t* X = lds_ + nxt * XBUFD + pt_l * PBS + (q_l << 1);
        #pragma unroll
        for (int i = 0; i < 5; ++i) if (i < NC) wr1(X, 12 + i, vC[i]);
    };

    // ---- tile 0 loads in flight across the whole weight prologue ----
    issueA(0); issueB(0); issueC(0);

    // ---- weight prologue via transient LDS overlay on buffer 1 ----
    bf16_t* trs = (bf16_t*)(lds_ + XBUFD);
    // W1, rows PERMUTED: slot s=(rt*16+4q+i) holds out-chan 32*(rt>>1)+8q+4*(rt&1)+i
    for (int i = tid; i < 64 * 96; i += 256) {
        int s = i / 96, c = i - s * 96;
        int rt = s >> 4, rr = s & 15, qq = rr >> 2, ii = rr & 3;
        int o = 32 * (rt >> 1) + 8 * qq + 4 * (rt & 1) + ii;
        trs[i] = (c < CX) ? (bf16_t)W1[o * CX + c] : (bf16_t)0.f;
    }
    __syncthreads();
    bf16x8 w1f[3][4];
    #pragma unroll
    for (int kc = 0; kc < 3; ++kc)
        #pragma unroll
        for (int rt = 0; rt < 4; ++rt)
            w1f[kc][rt] = *(const bf16x8*)&trs[(rt * 16 + lrow) * 96 + kc * 32 + g * 8];
    __syncthreads();
    for (int i = tid; i < 128 * 72; i += 256) {
        int o = i / 72, c = i - o * 72;
        trs[i] = (c < CMID) ? (bf16_t)W2[o * CMID + c] : (bf16_t)0.f;
    }
    __syncthreads();
    bf16x8 w2f[2][8];
    #pragma unroll
    for (int ot = 0; ot < 8; ++ot) {
        w2f[0][ot] = *(const bf16x8*)&trs[(ot * 16 + lrow) * 72 +  0 + g * 8];
        w2f[1][ot] = *(const bf16x8*)&trs[(ot * 16 + lrow) * 72 + 32 + g * 8];
    }
    __syncthreads();
    // write tile 0 (loads long since landed under the prologue)
    writeA(0); writeB(0); writeC(0);

    f32x4 b1f[4];   // permuted to match W1 row order
    #pragma unroll
    for (int rt = 0; rt < 4; ++rt)
        b1f[rt] = *(const f32x4*)(b1 + 32 * (rt >> 1) + 8 * g + 4 * (rt & 1));
    float b2f[8];
    #pragma unroll
    for (int ot = 0; ot < 8; ++ot) b2f[ot] = b2[ot * 16 + lrow];
    __syncthreads();

    // ---- per-point compute: LDS pair-dwords -> unzip -> MFMA -> pool -> store ----
    auto compute = [&](int cur, int t, int pt) {
        const int n = n0 + t * NT + pt;
        const uint32_t* Xc = lds_ + cur * XBUFD + pt * PBS + lrow;

        bf16x8 f0[3], f1[3];
        #pragma unroll
        for (int kc = 0; kc < 2; ++kc) {
            uint32_t d[8];
            #pragma unroll
            for (int e = 0; e < 8; ++e) d[e] = Xc[(kc * 32 + g * 8 + e) * 16];
            union { uint32_t u[4]; bf16x8 w; } c0, c1;
            #pragma unroll
            for (int p = 0; p < 4; ++p) {
                uint32_t a = d[2 * p], c = d[2 * p + 1];
                c0.u[p] = (a & 0xFFFFu) | (c << 16);          // even kpos lane
                c1.u[p] = (a >> 16)     | (c & 0xFFFF0000u);  // odd  kpos lane
            }
            f0[kc] = c0.w; f1[kc] = c1.w;
        }
        {   // kc=2: only g==0 carries real chans (64..66); all else EXACT ZERO
            // (W1 cols 67..95 are zero; garbage here becomes 0xNaN -> fmax-laundered
            //  wrong outputs — the R8 bug. Never feed unstaged LDS to the MFMA.)
            uint32_t d0 = 0, d1 = 0, d2 = 0;
            if (g == 0) {
                d0 = Xc[64 * 16];
                d1 = Xc[65 * 16];
                d2 = Xc[66 * 16];
            }
            union { uint32_t u[4]; bf16x8 w; } c0, c1;
            c0.u[0] = (d0 & 0xFFFFu) | (d1 << 16);
            c0.u[1] = (d2 & 0xFFFFu);
            c0.u[2] = 0; c0.u[3] = 0;
            c1.u[0] = (d0 >> 16) | (d1 & 0xFFFF0000u);
            c1.u[1] = (d2 >> 16);
            c1.u[2] = 0; c1.u[3] = 0;
            f0[2] = c0.w; f1[2] = c1.w;
        }

        // layer 1 + epilogue, half 0 then half 1 (keeps acc live-range small)
        bf16x8 a2f0[2], a2f1[2];
        {
            f32x4 acc[4] = {};
            __builtin_amdgcn_s_setprio(1);
            #pragma unroll
            for (int kc = 0; kc < 3; ++kc)
                #pragma unroll
                for (int rt = 0; rt < 4; ++rt)
                    acc[rt] = __builtin_amdgcn_mfma_f32_16x16x32_bf16(w1f[kc][rt], f0[kc], acc[rt], 0, 0, 0);
            __builtin_amdgcn_s_setprio(0);
            #pragma unroll
            for (int kc2 = 0; kc2 < 2; ++kc2) {
                union { uint32_t u[4]; bf16x8 w; } cc;
                #pragma unroll
                for (int hh = 0; hh < 2; ++hh) {
                    const int rt = 2 * kc2 + hh;
                    float h0 = fmaxf(acc[rt][0] + b1f[rt][0], 0.f);
                    float h1 = fmaxf(acc[rt][1] + b1f[rt][1], 0.f);
                    float h2 = fmaxf(acc[rt][2] + b1f[rt][2], 0.f);
                    float h3 = fmaxf(acc[rt][3] + b1f[rt][3], 0.f);
                    cc.u[hh * 2 + 0] = pack2bf(h0, h1);
                    cc.u[hh * 2 + 1] = pack2bf(h2, h3);
                }
                a2f0[kc2] = cc.w;
            }
        }
        {
            f32x4 acc[4] = {};
            __builtin_amdgcn_s_setprio(1);
            #pragma unroll
            for (int kc = 0; kc < 3; ++kc)
                #pragma unroll
                for (int rt = 0; rt < 4; ++rt)
                    acc[rt] = __builtin_amdgcn_mfma_f32_16x16x32_bf16(w1f[kc][rt], f1[kc], acc[rt], 0, 0, 0);
            __builtin_amdgcn_s_setprio(0);
            #pragma unroll
            for (int kc2 = 0; kc2 < 2; ++kc2) {
                union { uint32_t u[4]; bf16x8 w; } cc;
                #pragma unroll
                for (int hh = 0; hh < 2; ++hh) {
                    const int rt = 2 * kc2 + hh;
                    float h0 = fmaxf(acc[rt][0] + b1f[rt][0], 0.f);
                    float h1 = fmaxf(acc[rt][1] + b1f[rt][1], 0.f);
                    float h2 = fmaxf(acc[rt][2] + b1f[rt][2], 0.f);
                    float h3 = fmaxf(acc[rt][3] + b1f[rt][3], 0.f);
                    cc.u[hh * 2 + 0] = pack2bf(h0, h1);
                    cc.u[hh * 2 + 1] = pack2bf(h2, h3);
                }
                a2f1[kc2] = cc.w;
            }
        }

        // layer 2: A = packed H (regs), B = W2 (regs); D rows = k-positions
        float macc[8];
        __builtin_amdgcn_s_setprio(1);
        #pragma unroll
        for (int ot = 0; ot < 8; ++ot) {
            f32x4 t0 = {}, t1 = {};
            t0 = __builtin_amdgcn_mfma_f32_16x16x32_bf16(a2f0[0], w2f[0][ot], t0, 0, 0, 0);
            t0 = __builtin_amdgcn_mfma_f32_16x16x32_bf16(a2f0[1], w2f[1][ot], t0, 0, 0, 0);
            t1 = __builtin_amdgcn_mfma_f32_16x16x32_bf16(a2f1[0], w2f[0][ot], t1, 0, 0, 0);
            t1 = __builtin_amdgcn_mfma_f32_16x16x32_bf16(a2f1[1], w2f[1][ot], t1, 0, 0, 0);
            float m0 = fmaxf(fmaxf(t0[0], t0[1]), fmaxf(t0[2], t0[3]));
            float m1 = fmaxf(fmaxf(t1[0], t1[1]), fmaxf(t1[2], t1[3]));
            macc[ot] = fmaxf(m0, m1);
        }
        __builtin_amdgcn_s_setprio(0);

        // cross-group pool (xor16 + xor32), bias, relu
        #pragma unroll
        for (int ot = 0; ot < 8; ++ot) {
            float vv = macc[ot];
            vv = fmaxf(vv, __shfl_xor(vv, 16, 64));
            vv = fmaxf(vv, __shfl_xor(vv, 32, 64));
            macc[ot] = fmaxf(vv + b2f[ot], 0.f);
        }
        float oa = (g == 0) ? macc[0] : (g == 1) ? macc[2] : (g == 2) ? macc[4] : macc[6];
        float ob = (g == 0) ? macc[1] : (g == 1) ? macc[3] : (g == 2) ? macc[5] : macc[7];
        const int ca = g * 32 + lrow;
        const int cb2 = g * 32 + 16 + lrow;
        if (DIRECT) {
            float* op = dst + (size_t)b * COUT * N_ + n;
            op[(size_t)ca * N_]  = oa;
            op[(size_t)cb2 * N_] = ob;
        } else {
            float* wp = dst + ((size_t)(b * N_ + n)) * COUT;   // ws[b][n][c]
            wp[ca]  = oa;
            wp[cb2] = ob;
        }
    };

    // ---- main loop: stage(t+1) interleaved with the two compute points of t ----
    int cur = 0;
    #pragma unroll 1
    for (int t = 0; t < TPW; ++t) {
        const bool more = (t + 1 < TPW);
        if (more) issueA(t + 1);
        compute(cur, t, wave);                       // point p0 = wave
        if (more) { writeA(cur ^ 1); issueB(t + 1); }
        compute(cur, t, wave + 4);                   // point p1 = wave+4
        if (more) { writeB(cur ^ 1); issueC(t + 1); writeC(cur ^ 1); }
        __syncthreads();
        cur ^= 1;
    }
}

// ws[b][n][c] -> out[b][c][n], full lines on both sides
__global__ __launch_bounds__(256)
void sa_transpose(const float* __restrict__ ws, float* __restrict__ out)
{
    __shared__ float tile[32][136];
    const int t  = threadIdx.x;
    const int i  = blockIdx.x;         // 0..1023
    const int b  = i >> 8;
    const int n0 = (i & 255) << 5;

    const float* rp = ws + ((size_t)(b * N_ + n0)) * COUT;
    #pragma unroll
    for (int r = 0; r < 4; ++r) {
        int flat = (r * 256 + t) * 4;
        int nl = flat >> 7, c = flat & 127;
        float4 v = *(const float4*)(rp + (size_t)nl * COUT + c);
        *(float4*)&tile[nl][c] = v;
    }
    __syncthreads();
    float* op = out + (size_t)b * COUT * N_ + n0;
    const int nl4 = (t & 7) << 2;
    #pragma unroll
    for (int r2 = 0; r2 < 4; ++r2) {
        int c = r2 * 32 + (t >> 3);
        float4 o4;
        o4.x = tile[nl4 + 0][c];
        o4.y = tile[nl4 + 1][c];
        o4.z = tile[nl4 + 2][c];
        o4.w = tile[nl4 + 3][c];
        *(float4*)(op + (size_t)c * N_ + nl4) = o4;
    }
}

extern "C" void kernel_launch(void* const* d_in, const int* in_sizes, int n_in,
                              void* d_out, int out_size, void* d_ws, size_t ws_size,
                              hipStream_t stream) {
    // inputs: 0=p (unused), 1=f (unused), 2=dp, 3=fj, 4=W1, 5=b1, 6=W2, 7=b2
    const float* dp = (const float*)d_in[2];
    const float* fj = (const float*)d_in[3];
    const float* W1 = (const float*)d_in[4];
    const float* b1 = (const float*)d_in[5];
    const float* W2 = (const float*)d_in[6];
    const float* b2 = (const float*)d_in[7];
    float* out = (float*)d_out;

    const size_t ws_need = (size_t)B_ * N_ * COUT * sizeof(float);
    if (ws_size >= ws_need) {
        float* ws = (float*)d_ws;
        hipLaunchKernelGGL((sa_main<false>), dim3(NWGM), dim3(256), 0, stream,
                           dp, fj, W1, b1, W2, b2, ws);
        hipLaunchKernelGGL(sa_transpose, dim3(1024), dim3(256), 0, stream, ws, out);
    } else {
        hipLaunchKernelGGL((sa_main<true>), dim3(NWGM), dim3(256), 0, stream,
                           dp, fj, W1, b1, W2, b2, out);
    }
}

// Round 10
// 112.496 us; speedup vs baseline: 2.0790x; 1.3778x over previous
//
#include <hip/hip_runtime.h>
#include <hip/hip_bf16.h>
#include <stdint.h>

#define B_    4
#define N_    8192
#define K_    32
#define CX    67      // 3 + C_IN
#define CMID  64
#define COUT  128

#define CSTR  104     // Xs k-row stride (elems): 208B rows -> every row 16B-aligned (b128 reads)
#define TPG   8       // points per wave per WG
#define NWG   1024
#define GMAX  8191

typedef __bf16 bf16_t;
typedef bf16_t bf16x8 __attribute__((ext_vector_type(8)));
typedef float  f32x4  __attribute__((ext_vector_type(4)));

__device__ __forceinline__ uint32_t pack2bf(float a, float b) {
    union { bf16_t h[2]; uint32_t u; } x;
    x.h[0] = (bf16_t)a; x.h[1] = (bf16_t)b;
    return x.u;
}

template<bool DIRECT>
__global__ __launch_bounds__(256, 2)
void sa_main(const float* __restrict__ dp, const float* __restrict__ fj,
             const float* __restrict__ W1, const float* __restrict__ b1,
             const float* __restrict__ W2, const float* __restrict__ b2,
             float* __restrict__ dst)
{
    // LDS: X staging only (4 waves x 32 k-rows x CSTR). Weights pass through
    // transient overlays of this region during the prologue, then live in regs.
    __shared__ bf16_t smem[4 * 32 * CSTR];   // 26,624 B

    const int tid  = threadIdx.x;
    const int wave = tid >> 6;
    const int lane = tid & 63;
    const int lrow = lane & 15;   // MFMA row/col within 16-tile; kpos pair {2*lrow, 2*lrow+1}
    const int g    = lane >> 4;   // 16-lane group (fragment k-group)

    bf16_t* Xw = smem + wave * 32 * CSTR;

    const size_t plane = (size_t)N_ * K_;
    const int bidx = blockIdx.x;
    const int b    = (bidx * TPG) >> 11;    // batch constant per WG (TPG | 2048)

    const int cr = lane >> 3;            // staging: channel-in-group 0..7
    const int k0 = (lane & 7) << 2;      // staging: k base 0..28

    // ---- slim issuer (R3-verified): one dp/fj select (j=0), one clamp (j=8) ----
    float4 v[9];
    auto issue = [&](int Gi) {
        const int bb = Gi >> 11;
        const int nn = ((Gi & 2047) << 2) + wave;
        const size_t rbase = (size_t)nn * K_ + k0;
        const float* fp  = fj + (size_t)bb * 64 * plane + rbase;
        const float* dp0 = dp + (size_t)bb * 3  * plane + rbase;
        const float* p0 = (cr < 3) ? dp0 + (size_t)cr * plane
                                   : fp  + (size_t)(cr - 3) * plane;
        v[0] = *(const float4*)p0;
        const float* pj = fp + (size_t)(8 + cr - 3) * plane;
        #pragma unroll
        for (int j = 1; j < 8; ++j) {
            v[j] = *(const float4*)pj;
            pj += 8 * plane;
        }
        const int c8 = (cr < 3) ? (64 + cr) : 66;   // clamp: line already fetched
        v[8] = *(const float4*)(fp + (size_t)(c8 - 3) * plane);
    };

    // t=0 loads in flight across the whole weight prologue
    issue(bidx * TPG);

    // ---- prologue: W1 (PERMUTED rows) via transient overlay -> regs ----
    // slot s=(rt*16+4q+i) holds out-chan pi = 32*(rt>>1)+8q+4*(rt&1)+i
    for (int i = tid; i < 64 * 96; i += 256) {
        int s = i / 96, c = i - s * 96;
        int rt = s >> 4, rr = s & 15, qq = rr >> 2, ii = rr & 3;
        int o = 32 * (rt >> 1) + 8 * qq + 4 * (rt & 1) + ii;
        smem[i] = (c < CX) ? (bf16_t)W1[o * CX + c] : (bf16_t)0.f;
    }
    __syncthreads();
    bf16x8 w1f[3][4];
    #pragma unroll
    for (int kc = 0; kc < 3; ++kc)
        #pragma unroll
        for (int rt = 0; rt < 4; ++rt)
            w1f[kc][rt] = *(const bf16x8*)&smem[(rt * 16 + lrow) * 96 + kc * 32 + g * 8];
    __syncthreads();
    // W2 [out][mid] via transient overlay -> regs (B operand of layer-2 MFMA)
    for (int i = tid; i < 128 * 72; i += 256) {
        int o = i / 72, c = i - o * 72;
        smem[i] = (c < CMID) ? (bf16_t)W2[o * CMID + c] : (bf16_t)0.f;
    }
    __syncthreads();
    bf16x8 w2f[2][8];
    #pragma unroll
    for (int kcc = 0; kcc < 2; ++kcc)
        #pragma unroll
        for (int ot = 0; ot < 8; ++ot)
            w2f[kcc][ot] = *(const bf16x8*)&smem[(ot * 16 + lrow) * 72 + kcc * 32 + g * 8];
    __syncthreads();
    // zero Xs (pad chans 67..103 stay zero FOREVER; 0..66 rewritten each point.
    // kc=2 fragment reads span chans 64..95 -> pads must be exact zero, R8 lesson)
    for (int i = tid; i < 4 * 32 * CSTR; i += 256) smem[i] = (bf16_t)0.f;
    __syncthreads();

    f32x4 b1f[4];   // permuted to match W1 row order
    #pragma unroll
    for (int rt = 0; rt < 4; ++rt)
        b1f[rt] = *(const f32x4*)(b1 + 32 * (rt >> 1) + 8 * g + 4 * (rt & 1));
    float b2f[8];
    #pragma unroll
    for (int ot = 0; ot < 8; ++ot) b2f[ot] = b2[ot * 16 + lrow];

    #pragma unroll 1
    for (int t = 0; t < TPG; ++t) {
        const int G = bidx * TPG + t;
        const int n = ((G & 2047) << 2) + wave;

        // ---- stage current v -> Xw [k][chan] (consumes v; wave-private) ----
        #pragma unroll
        for (int j = 0; j < 9; ++j) {
            int c = j * 8 + cr;
            if (c < CX) {
                Xw[(k0 + 0) * CSTR + c] = (bf16_t)v[j].x;
                Xw[(k0 + 1) * CSTR + c] = (bf16_t)v[j].y;
                Xw[(k0 + 2) * CSTR + c] = (bf16_t)v[j].z;
                Xw[(k0 + 3) * CSTR + c] = (bf16_t)v[j].w;
            }
        }
        // ---- reissue for next point: hides under this point's compute ----
        { int Gn = G + 1; if (Gn > GMAX) Gn = GMAX; issue(Gn); }

        // ---- X B-frags: col s=lrow <- kpos 2s (f0) / 2s+1 (f1); single b128 each ----
        bf16x8 f0[3], f1[3];
        #pragma unroll
        for (int kc = 0; kc < 3; ++kc) {
            f0[kc] = *(const bf16x8*)&Xw[(2 * lrow)     * CSTR + kc * 32 + g * 8];
            f1[kc] = *(const bf16x8*)&Xw[(2 * lrow + 1) * CSTR + kc * 32 + g * 8];
        }

        // ---- layer 1 + epilogue, half 0 (even kpos) then half 1 (odd) ----
        bf16x8 a2f0[2], a2f1[2];
        {
            f32x4 acc[4] = {};
            __builtin_amdgcn_s_setprio(1);
            #pragma unroll
            for (int kc = 0; kc < 3; ++kc)
                #pragma unroll
                for (int rt = 0; rt < 4; ++rt)
                    acc[rt] = __builtin_amdgcn_mfma_f32_16x16x32_bf16(w1f[kc][rt], f0[kc], acc[rt], 0, 0, 0);
            __builtin_amdgcn_s_setprio(0);
            #pragma unroll
            for (int kc2 = 0; kc2 < 2; ++kc2) {
                union { uint32_t u[4]; bf16x8 w; } cc;
                #pragma unroll
                for (int hh = 0; hh < 2; ++hh) {
                    const int rt = 2 * kc2 + hh;
                    float h0 = fmaxf(acc[rt][0] + b1f[rt][0], 0.f);
                    float h1 = fmaxf(acc[rt][1] + b1f[rt][1], 0.f);
                    float h2 = fmaxf(acc[rt][2] + b1f[rt][2], 0.f);
                    float h3 = fmaxf(acc[rt][3] + b1f[rt][3], 0.f);
                    cc.u[hh * 2 + 0] = pack2bf(h0, h1);
                    cc.u[hh * 2 + 1] = pack2bf(h2, h3);
                }
                a2f0[kc2] = cc.w;
            }
        }
        {
            f32x4 acc[4] = {};
            __builtin_amdgcn_s_setprio(1);
            #pragma unroll
            for (int kc = 0; kc < 3; ++kc)
                #pragma unroll
                for (int rt = 0; rt < 4; ++rt)
                    acc[rt] = __builtin_amdgcn_mfma_f32_16x16x32_bf16(w1f[kc][rt], f1[kc], acc[rt], 0, 0, 0);
            __builtin_amdgcn_s_setprio(0);
            #pragma unroll
            for (int kc2 = 0; kc2 < 2; ++kc2) {
                union { uint32_t u[4]; bf16x8 w; } cc;
                #pragma unroll
                for (int hh = 0; hh < 2; ++hh) {
                    const int rt = 2 * kc2 + hh;
                    float h0 = fmaxf(acc[rt][0] + b1f[rt][0], 0.f);
                    float h1 = fmaxf(acc[rt][1] + b1f[rt][1], 0.f);
                    float h2 = fmaxf(acc[rt][2] + b1f[rt][2], 0.f);
                    float h3 = fmaxf(acc[rt][3] + b1f[rt][3], 0.f);
                    cc.u[hh * 2 + 0] = pack2bf(h0, h1);
                    cc.u[hh * 2 + 1] = pack2bf(h2, h3);
                }
                a2f1[kc2] = cc.w;
            }
        }

        // ---- layer 2: A = packed H (regs), B = W2 (regs); D rows = kpos slots ----
        float macc[8];
        __builtin_amdgcn_s_setprio(1);
        #pragma unroll
        for (int ot = 0; ot < 8; ++ot) {
            f32x4 t0 = {}, t1 = {};
            t0 = __builtin_amdgcn_mfma_f32_16x16x32_bf16(a2f0[0], w2f[0][ot], t0, 0, 0, 0);
            t0 = __builtin_amdgcn_mfma_f32_16x16x32_bf16(a2f0[1], w2f[1][ot], t0, 0, 0, 0);
            t1 = __builtin_amdgcn_mfma_f32_16x16x32_bf16(a2f1[0], w2f[0][ot], t1, 0, 0, 0);
            t1 = __builtin_amdgcn_mfma_f32_16x16x32_bf16(a2f1[1], w2f[1][ot], t1, 0, 0, 0);
            float m0 = fmaxf(fmaxf(t0[0], t0[1]), fmaxf(t0[2], t0[3]));
            float m1 = fmaxf(fmaxf(t1[0], t1[1]), fmaxf(t1[2], t1[3]));
            macc[ot] = fmaxf(m0, m1);   // in-lane pool over this lane's 8 kpos
        }
        __builtin_amdgcn_s_setprio(0);

        // ---- cross-group pool (xor16 + xor32), bias, relu ----
        #pragma unroll
        for (int ot = 0; ot < 8; ++ot) {
            float vv = macc[ot];
            vv = fmaxf(vv, __shfl_xor(vv, 16, 64));
            vv = fmaxf(vv, __shfl_xor(vv, 32, 64));
            macc[ot] = fmaxf(vv + b2f[ot], 0.f);
        }
        float oa = (g == 0) ? macc[0] : (g == 1) ? macc[2] : (g == 2) ? macc[4] : macc[6];
        float ob = (g == 0) ? macc[1] : (g == 1) ? macc[3] : (g == 2) ? macc[5] : macc[7];
        const int ca  = g * 32 + lrow;
        const int cb2 = g * 32 + 16 + lrow;
        if (DIRECT) {
            float* op = dst + (size_t)b * COUT * N_ + n;
            op[(size_t)ca  * N_] = oa;
            op[(size_t)cb2 * N_] = ob;
        } else {
            float* wp = dst + ((size_t)(b * N_ + n)) * COUT;   // ws[b][n][c]
            wp[ca]  = oa;
            wp[cb2] = ob;
        }
    }
}

// ws[b][n][c] -> out[b][c][n], full lines on both sides
__global__ __launch_bounds__(256)
void sa_transpose(const float* __restrict__ ws, float* __restrict__ out)
{
    __shared__ float tile[32][136];
    const int t  = threadIdx.x;
    const int i  = blockIdx.x;         // 0..1023
    const int b  = i >> 8;
    const int n0 = (i & 255) << 5;

    const float* rp = ws + ((size_t)(b * N_ + n0)) * COUT;
    #pragma unroll
    for (int r = 0; r < 4; ++r) {
        int flat = (r * 256 + t) * 4;
        int nl = flat >> 7, c = flat & 127;
        float4 v = *(const float4*)(rp + (size_t)nl * COUT + c);
        *(float4*)&tile[nl][c] = v;
    }
    __syncthreads();
    float* op = out + (size_t)b * COUT * N_ + n0;
    const int nl4 = (t & 7) << 2;
    #pragma unroll
    for (int r2 = 0; r2 < 4; ++r2) {
        int c = r2 * 32 + (t >> 3);
        float4 o4;
        o4.x = tile[nl4 + 0][c];
        o4.y = tile[nl4 + 1][c];
        o4.z = tile[nl4 + 2][c];
        o4.w = tile[nl4 + 3][c];
        *(float4*)(op + (size_t)c * N_ + nl4) = o4;
    }
}

extern "C" void kernel_launch(void* const* d_in, const int* in_sizes, int n_in,
                              void* d_out, int out_size, void* d_ws, size_t ws_size,
                              hipStream_t stream) {
    // inputs: 0=p (unused), 1=f (unused), 2=dp, 3=fj, 4=W1, 5=b1, 6=W2, 7=b2
    const float* dp = (const float*)d_in[2];
    const float* fj = (const float*)d_in[3];
    const float* W1 = (const float*)d_in[4];
    const float* b1 = (const float*)d_in[5];
    const float* W2 = (const float*)d_in[6];
    const float* b2 = (const float*)d_in[7];
    float* out = (float*)d_out;

    const size_t ws_need = (size_t)B_ * N_ * COUT * sizeof(float);
    if (ws_size >= ws_need) {
        float* ws = (float*)d_ws;
        hipLaunchKernelGGL((sa_main<false>), dim3(NWG), dim3(256), 0, stream,
                           dp, fj, W1, b1, W2, b2, ws);
        hipLaunchKernelGGL(sa_transpose, dim3(1024), dim3(256), 0, stream, ws, out);
    } else {
        hipLaunchKernelGGL((sa_main<true>), dim3(NWG), dim3(256), 0, stream,
                           dp, fj, W1, b1, W2, b2, out);
    }
}